// Round 1
// baseline (363.194 us; speedup 1.0000x reference)
//
#include <hip/hip_runtime.h>
#include <math.h>

// ws float layout:
//  [0]      E_sum
//  [1]      tr_gp
//  [2..17]  m[16]
//  [18..33] cs[16]
//  [64..2112)   B[16][128]   (atomic-accumulated, zeroed)
//  [2112..4160) P2[16][128]  (written by finalize, no zero needed)

#define WS_ESUM 0
#define WS_TR   1
#define WS_M    2
#define WS_CS   18
#define WS_B    64
#define WS_P2   2112

// ---------------------------------------------------------------- k_assign
// A[n,:] = softmax(F[n,:] @ W^T + b); cs[k] += sum_n A[n,k]
__global__ __launch_bounds__(256) void k_assign(
    const float* __restrict__ F, const float* __restrict__ W,
    const float* __restrict__ bias, float* __restrict__ A,
    float* __restrict__ cs, int N) {
  __shared__ float Ws[2048];       // fc_w [16][128]
  __shared__ float csred[4][16];
  int t = threadIdx.x;
#pragma unroll
  for (int i = 0; i < 8; i++) Ws[t + 256 * i] = W[t + 256 * i];
  __syncthreads();

  int n = blockIdx.x * 256 + t;
  float a[16];
  if (n < N) {
#pragma unroll
    for (int k = 0; k < 16; k++) a[k] = bias[k];
    const float4* f4 = (const float4*)(F + (size_t)n * 128);
#pragma unroll 4
    for (int i = 0; i < 32; i++) {
      float4 f = f4[i];
#pragma unroll
      for (int k = 0; k < 16; k++) {
        float4 w = *(const float4*)(&Ws[k * 128 + i * 4]);
        a[k] = fmaf(f.x, w.x, a[k]);
        a[k] = fmaf(f.y, w.y, a[k]);
        a[k] = fmaf(f.z, w.z, a[k]);
        a[k] = fmaf(f.w, w.w, a[k]);
      }
    }
    // softmax
    float mx = a[0];
#pragma unroll
    for (int k = 1; k < 16; k++) mx = fmaxf(mx, a[k]);
    float s = 0.f;
#pragma unroll
    for (int k = 0; k < 16; k++) { a[k] = __expf(a[k] - mx); s += a[k]; }
    float inv = 1.0f / s;
#pragma unroll
    for (int k = 0; k < 16; k++) a[k] *= inv;
    float4* o = (float4*)(A + (size_t)n * 16);
    o[0] = make_float4(a[0], a[1], a[2], a[3]);
    o[1] = make_float4(a[4], a[5], a[6], a[7]);
    o[2] = make_float4(a[8], a[9], a[10], a[11]);
    o[3] = make_float4(a[12], a[13], a[14], a[15]);
  } else {
#pragma unroll
    for (int k = 0; k < 16; k++) a[k] = 0.f;
  }

  // cluster sizes: wave butterfly, then cross-wave via LDS, then atomic
#pragma unroll
  for (int k = 0; k < 16; k++) {
    float v = a[k];
    for (int off = 32; off; off >>= 1) v += __shfl_xor(v, off, 64);
    a[k] = v;
  }
  int lane = t & 63, wid = t >> 6;
  if (lane == 0) {
#pragma unroll
    for (int k = 0; k < 16; k++) csred[wid][k] = a[k];
  }
  __syncthreads();
  if (t < 16)
    atomicAdd(&cs[t], csred[0][t] + csred[1][t] + csred[2][t] + csred[3][t]);
}

// ---------------------------------------------------------------- k_edge
// E_sum = sum val;  m[k] = sum val*A[col,k];  tr = sum val*dot(A[row],A[col])
__global__ __launch_bounds__(256) void k_edge(
    const int* __restrict__ row, const int* __restrict__ col,
    const float* __restrict__ val, const float* __restrict__ A,
    float* __restrict__ ws, int E) {
  float eS = 0.f, tr = 0.f;
  float m[16];
#pragma unroll
  for (int i = 0; i < 16; i++) m[i] = 0.f;

  int tid = blockIdx.x * 256 + threadIdx.x;
  int T = gridDim.x * 256;
  for (int e = tid; e < E; e += T) {
    int r = row[e], c = col[e];
    float v = val[e];
    const float4* Ac4 = (const float4*)(A + (size_t)c * 16);
    const float4* Ar4 = (const float4*)(A + (size_t)r * 16);
    float4 c0 = Ac4[0], c1 = Ac4[1], c2 = Ac4[2], c3 = Ac4[3];
    float4 r0 = Ar4[0], r1 = Ar4[1], r2 = Ar4[2], r3 = Ar4[3];
    eS += v;
    m[0]  = fmaf(v, c0.x, m[0]);  m[1]  = fmaf(v, c0.y, m[1]);
    m[2]  = fmaf(v, c0.z, m[2]);  m[3]  = fmaf(v, c0.w, m[3]);
    m[4]  = fmaf(v, c1.x, m[4]);  m[5]  = fmaf(v, c1.y, m[5]);
    m[6]  = fmaf(v, c1.z, m[6]);  m[7]  = fmaf(v, c1.w, m[7]);
    m[8]  = fmaf(v, c2.x, m[8]);  m[9]  = fmaf(v, c2.y, m[9]);
    m[10] = fmaf(v, c2.z, m[10]); m[11] = fmaf(v, c2.w, m[11]);
    m[12] = fmaf(v, c3.x, m[12]); m[13] = fmaf(v, c3.y, m[13]);
    m[14] = fmaf(v, c3.z, m[14]); m[15] = fmaf(v, c3.w, m[15]);
    float d = r0.x * c0.x + r0.y * c0.y + r0.z * c0.z + r0.w * c0.w
            + r1.x * c1.x + r1.y * c1.y + r1.z * c1.z + r1.w * c1.w
            + r2.x * c2.x + r2.y * c2.y + r2.z * c2.z + r2.w * c2.w
            + r3.x * c3.x + r3.y * c3.y + r3.z * c3.z + r3.w * c3.w;
    tr = fmaf(v, d, tr);
  }

  float vals[18];
  vals[0] = eS; vals[1] = tr;
#pragma unroll
  for (int i = 0; i < 16; i++) vals[2 + i] = m[i];
#pragma unroll
  for (int i = 0; i < 18; i++) {
    float v = vals[i];
    for (int off = 32; off; off >>= 1) v += __shfl_xor(v, off, 64);
    vals[i] = v;
  }
  __shared__ float red[4][18];
  int lane = threadIdx.x & 63, wid = threadIdx.x >> 6;
  if (lane == 0) {
#pragma unroll
    for (int i = 0; i < 18; i++) red[wid][i] = vals[i];
  }
  __syncthreads();
  if (threadIdx.x < 18)
    atomicAdd(&ws[threadIdx.x],
              red[0][threadIdx.x] + red[1][threadIdx.x] +
              red[2][threadIdx.x] + red[3][threadIdx.x]);
}

// ---------------------------------------------------------------- k_nodeB
// B[k,c] = sum_n A[n,k] * F[n,c]   (16 x 128)
// Each wave owns all 2048 cells: lane -> cb = (lane&15)*8 (8 channels),
// kb = (lane>>4)*4 (4 clusters) => 32 accumulators/lane.
__global__ __launch_bounds__(256) void k_nodeB(
    const float* __restrict__ F, const float* __restrict__ A,
    float* __restrict__ B, int N) {
  int t = threadIdx.x;
  int lane = t & 63, wid = t >> 6;
  int gw = blockIdx.x * 4 + wid;
  int nw = gridDim.x * 4;
  int cb = (lane & 15) * 8;
  int kb = (lane >> 4) * 4;

  float4 acc[4][2];
#pragma unroll
  for (int j = 0; j < 4; j++) {
    acc[j][0] = make_float4(0.f, 0.f, 0.f, 0.f);
    acc[j][1] = make_float4(0.f, 0.f, 0.f, 0.f);
  }

  for (int n = gw; n < N; n += nw) {
    const float* Fr = F + (size_t)n * 128 + cb;
    float4 f0 = *(const float4*)Fr;
    float4 f1 = *(const float4*)(Fr + 4);
    float4 a4 = *(const float4*)(A + (size_t)n * 16 + kb);
    float av[4] = {a4.x, a4.y, a4.z, a4.w};
#pragma unroll
    for (int j = 0; j < 4; j++) {
      acc[j][0].x = fmaf(av[j], f0.x, acc[j][0].x);
      acc[j][0].y = fmaf(av[j], f0.y, acc[j][0].y);
      acc[j][0].z = fmaf(av[j], f0.z, acc[j][0].z);
      acc[j][0].w = fmaf(av[j], f0.w, acc[j][0].w);
      acc[j][1].x = fmaf(av[j], f1.x, acc[j][1].x);
      acc[j][1].y = fmaf(av[j], f1.y, acc[j][1].y);
      acc[j][1].z = fmaf(av[j], f1.z, acc[j][1].z);
      acc[j][1].w = fmaf(av[j], f1.w, acc[j][1].w);
    }
  }

  __shared__ float red[4][2048];   // 32 KB
#pragma unroll
  for (int j = 0; j < 4; j++) {
    int idx = (kb + j) * 128 + cb;
    *(float4*)&red[wid][idx]     = acc[j][0];
    *(float4*)&red[wid][idx + 4] = acc[j][1];
  }
  __syncthreads();
#pragma unroll
  for (int q = 0; q < 2; q++) {
    int base = t * 8 + q * 4;
    float4 s0 = *(float4*)&red[0][base];
    float4 s1 = *(float4*)&red[1][base];
    float4 s2 = *(float4*)&red[2][base];
    float4 s3 = *(float4*)&red[3][base];
    atomicAdd(&B[base + 0], s0.x + s1.x + s2.x + s3.x);
    atomicAdd(&B[base + 1], s0.y + s1.y + s2.y + s3.y);
    atomicAdd(&B[base + 2], s0.z + s1.z + s2.z + s3.z);
    atomicAdd(&B[base + 3], s0.w + s1.w + s2.w + s3.w);
  }
}

// ---------------------------------------------------------------- k_finalize
// P2[k,c] = (1/cs[k]) * selu(B[k,c]/cs[k]);  loss scalar.
__global__ __launch_bounds__(256) void k_finalize(
    float* __restrict__ ws, float* __restrict__ loss_out, int N) {
  __shared__ float invcs[16];
  int t = threadIdx.x;
  if (t < 16) invcs[t] = 1.0f / ws[WS_CS + t];
  __syncthreads();
  const float* B = ws + WS_B;
  float* P2 = ws + WS_P2;
  const float scale = 1.0507009873554805f;
  const float alpha = 1.6732632423543772f;
#pragma unroll
  for (int idx = t; idx < 2048; idx += 256) {
    int k = idx >> 7;
    float x = B[idx] * invcs[k];
    float s = (x > 0.f) ? scale * x : scale * alpha * expm1f(x);
    P2[idx] = s * invcs[k];
  }
  if (t == 0) {
    float Es = ws[WS_ESUM], tr = ws[WS_TR];
    float m2 = 0.f;
#pragma unroll
    for (int i = 0; i < 16; i++) m2 += ws[WS_M + i] * ws[WS_M + i];
    float spectral = -(tr - m2 / (2.0f * Es)) / (2.0f * Es);
    float coll = 0.f;
    float tgt = (float)N / 16.0f;
#pragma unroll
    for (int i = 0; i < 16; i++) coll += fabsf(ws[WS_CS + i] - tgt);
    coll = coll / (float)N * (4.0f / 3.0f / 2.0f);  // sk/(sk-1)/2, sk=4
    loss_out[0] = spectral + coll;
  }
}

// ---------------------------------------------------------------- k_unpool
// out[n,c] = sum_k A[n,k] * P2[k,c]
__global__ __launch_bounds__(256) void k_unpool(
    const float* __restrict__ A, const float* __restrict__ P2,
    float* __restrict__ out, int N) {
  __shared__ float Ps[2048];
  int t = threadIdx.x;
#pragma unroll
  for (int i = 0; i < 8; i++) Ps[t + 256 * i] = P2[t + 256 * i];
  __syncthreads();
  int c = t & 127;
  int half = t >> 7;
  int pairs = (N + 1) >> 1;
  for (int p = blockIdx.x; p < pairs; p += gridDim.x) {
    int n = p * 2 + half;
    if (n < N) {
      const float4* a4 = (const float4*)(A + (size_t)n * 16);
      float4 a0 = a4[0], a1 = a4[1], a2 = a4[2], a3 = a4[3];
      float s = a0.x * Ps[0 * 128 + c] + a0.y * Ps[1 * 128 + c]
              + a0.z * Ps[2 * 128 + c] + a0.w * Ps[3 * 128 + c]
              + a1.x * Ps[4 * 128 + c] + a1.y * Ps[5 * 128 + c]
              + a1.z * Ps[6 * 128 + c] + a1.w * Ps[7 * 128 + c]
              + a2.x * Ps[8 * 128 + c] + a2.y * Ps[9 * 128 + c]
              + a2.z * Ps[10 * 128 + c] + a2.w * Ps[11 * 128 + c]
              + a3.x * Ps[12 * 128 + c] + a3.y * Ps[13 * 128 + c]
              + a3.z * Ps[14 * 128 + c] + a3.w * Ps[15 * 128 + c];
      out[(size_t)n * 128 + c] = s;
    }
  }
}

// ----------------------------------------------------------------
extern "C" void kernel_launch(void* const* d_in, const int* in_sizes, int n_in,
                              void* d_out, int out_size, void* d_ws, size_t ws_size,
                              hipStream_t stream) {
  const float* F    = (const float*)d_in[0];  // [N,128]
  const int*   erow = (const int*)d_in[1];    // [E]
  const int*   ecol = (const int*)d_in[2];    // [E]
  const float* eval_= (const float*)d_in[3];  // [E]
  const float* W    = (const float*)d_in[4];  // [16,128]
  const float* bias = (const float*)d_in[5];  // [16]

  int N = in_sizes[0] / 128;
  int E = in_sizes[1];

  float* out0 = (float*)d_out;                 // features_pooled [N,128]
  float* A    = out0 + (size_t)N * 128;        // assignments [N,16]
  float* loss = A + (size_t)N * 16;            // scalar
  float* ws   = (float*)d_ws;

  // zero the atomic accumulators: scalars/m/cs + B = (64 + 2048) floats
  hipMemsetAsync(d_ws, 0, (size_t)(WS_B + 2048) * sizeof(float), stream);

  k_assign<<<(N + 255) / 256, 256, 0, stream>>>(F, W, bias, A, ws + WS_CS, N);
  k_edge<<<1024, 256, 0, stream>>>(erow, ecol, eval_, A, ws, E);
  k_nodeB<<<512, 256, 0, stream>>>(F, A, ws + WS_B, N);
  k_finalize<<<1, 256, 0, stream>>>(ws, loss, N);
  k_unpool<<<512, 256, 0, stream>>>(A, ws + WS_P2, out0, N);
}